// Round 7
// baseline (142.721 us; speedup 1.0000x reference)
//
#include <hip/hip_runtime.h>
#include <cstdint>

#define BB 2
#define NN 4096
#define MM 4096
#define KK 32
#define CC 64
#define R2C 0.0064f   // RADIUS^2

typedef _Float16 v8h __attribute__((ext_vector_type(8)));
typedef _Float16 v4h __attribute__((ext_vector_type(4)));
typedef float    v4f __attribute__((ext_vector_type(4)));

#define TC  64     // MLP columns per pass
#define XS  104    // X  stride (f16): 96 + 8 pad
#define H1S 136    // H1 stride: 128 + 8
#define H2S 72     // H2 stride: 64 + 8

// ---------------------------------------------------------------------------
// Fused setup: one dispatch does all preprocessing.
//   blocks [  0, 32): pack points  (B,3,N)->float4{x,y,z,|p|^2}  (strict fp32)
//   blocks [ 32, 64): pack knn     (B,3,M)->float4
//   blocks [ 64,192): transpose feat (B,C,M) -> featH (B,M,C) f16
//   blocks [192,240): pack weights to f16 A-operand layouts
//   blocks [240,248): zero loss partials (+ ticket counter)
// ---------------------------------------------------------------------------
__launch_bounds__(256)
__global__ void setup_kernel(const float* __restrict__ points,
                             const float* __restrict__ knn,
                             const float* __restrict__ feat,
                             const float* __restrict__ w1,
                             const float* __restrict__ w2,
                             const float* __restrict__ w3,
                             float4* __restrict__ pointsT,
                             float4* __restrict__ knnT,
                             _Float16* __restrict__ featH,
                             _Float16* __restrict__ w1h,
                             _Float16* __restrict__ w2h,
                             _Float16* __restrict__ w3h,
                             float* __restrict__ lossbuf,
                             int* __restrict__ counter) {
    __shared__ float tile[64][65];
    int blk = blockIdx.x, t = threadIdx.x;
    if (blk < 64) {
        const float* src = (blk < 32) ? points : knn;
        float4* dst = (blk < 32) ? pointsT : knnT;
        int i = (blk & 31) * 256 + t;          // < 8192 = BB*4096
        int b = i >> 12, p = i & 4095;
        const float* base = src + (size_t)b * 3 * 4096;
        float x = base[p], y = base[4096 + p], z = base[8192 + p];
        float e = __fadd_rn(__fadd_rn(__fmul_rn(x, x), __fmul_rn(y, y)),
                            __fmul_rn(z, z));
        dst[i] = make_float4(x, y, z, e);
    } else if (blk < 192) {
        int tb = blk - 64;                      // 128 tiles
        int b = tb / (MM / 64);
        int m0 = (tb % (MM / 64)) * 64;
        int mi = t & 63, cq = t >> 6;
        const float* src = feat + (size_t)b * CC * MM;
#pragma unroll
        for (int r = 0; r < 16; ++r) {
            int c = cq * 16 + r;
            tile[mi][c] = src[(size_t)c * MM + m0 + mi];
        }
        __syncthreads();
        int ci = t & 63, mq = t >> 6;
        _Float16* dst = featH + ((size_t)b * MM + m0) * CC;
#pragma unroll
        for (int r = 0; r < 16; ++r) {
            int mm = mq * 16 + r;
            dst[(size_t)mm * CC + ci] = (_Float16)tile[mm][ci];
        }
    } else if (blk < 240) {
        int tt = (blk - 192) * 256 + t;         // < 12288
        if (tt < 128 * 96) {
            int r = tt / 96, k = tt - r * 96;
            w1h[tt] = (_Float16)((k < 68) ? w1[r * 68 + k] : 0.0f);
        }
        if (tt < 64 * 128) w2h[tt] = (_Float16)w2[tt];
        if (tt < 64 * 64)  w3h[tt] = (_Float16)w3[tt];
    } else {
        int i = ((blk - 240) * 256 + t) * 4;    // zero 8192 floats
        *(float4*)(lossbuf + i) = make_float4(0.f, 0.f, 0.f, 0.f);
        if (blk == 240 && t == 0) counter[0] = 0;
    }
}

// ---------------------------------------------------------------------------
// Fused main kernel:
//   blocks [  0, 512): SELECT 16 points (4/wave) — knnT read DIRECTLY from
//                      global (coalesced float4; VMEM pipe, frees the LDS
//                      pipe: R6's staged tiles caused 3.28M stride-16 8-way
//                      bank conflicts). Ballot-compaction of first-KK
//                      ascending in-radius m == reference top_k semantics;
//                      row-min -> loss. Then the MFMA MLP for the same 16
//                      points (8 passes x 64 cols), indices from LDS.
//   blocks [512,1024): COLMIN 16 m (4/wave, direct global reads) -> loss.
// Loss finalization via device-scope ticket counter (last of 1024 blocks
// reduces the partial slots with agent-scope atomic loads).
// launch_bounds (256,3): VGPR cap 170 — R6's (256,4) cap of 128 made the
// allocator spill the MLP A-fragments (VGPR_Count 56, MfmaUtil 7.5%).
// d2 math strict fp32, identical op order to reference.
// ---------------------------------------------------------------------------
__launch_bounds__(256, 3)
__global__ void fused_kernel(const float4* __restrict__ pointsT,
                             const float4* __restrict__ knnT,
                             const _Float16* __restrict__ featH,
                             const _Float16* __restrict__ w1h, const float* __restrict__ b1,
                             const _Float16* __restrict__ w2h, const float* __restrict__ b2,
                             const _Float16* __restrict__ w3h, const float* __restrict__ b3,
                             float* __restrict__ lossbuf,
                             int* __restrict__ counter,
                             float* __restrict__ out) {
    __shared__ __align__(16) _Float16 SM[TC * XS + TC * H1S];  // 30720 B
    __shared__ int sidx[16][KK];
    __shared__ float ws4v[4];
    __shared__ int rflag;
    _Float16* X  = SM;
    _Float16* H2 = SM;             // aliases X (dead after layer-1 barrier)
    _Float16* H1 = SM + TC * XS;

    int t = threadIdx.x;
    int w = t >> 6, lane = t & 63;
    int blk = blockIdx.x;

    if (blk < 512) {
        // ================ phase A: select 16 points ================
        int pt0 = blk * 16;                  // global point id (b*NN+n)
        int b = pt0 >> 12;
        float4 P[4];
#pragma unroll
        for (int p = 0; p < 4; ++p) P[p] = pointsT[pt0 + 4 * w + p];
        int cnt[4] = {0, 0, 0, 0};
        float mn[4] = {1e30f, 1e30f, 1e30f, 1e30f};
        const float4* kb = knnT + (size_t)b * MM;

#pragma unroll 2
        for (int c = 0; c < MM / 64; ++c) {
            int m = c * 64 + lane;
            float4 k4 = kb[m];
#pragma unroll
            for (int p = 0; p < 4; ++p) {
                float cross = __builtin_fmaf(P[p].z, k4.z,
                              __builtin_fmaf(P[p].y, k4.y,
                                             __fmul_rn(P[p].x, k4.x)));
                float d2 = __fsub_rn(__fadd_rn(P[p].w, k4.w),
                                     __fmul_rn(2.0f, cross));
                mn[p] = fminf(mn[p], d2);            // clamp once at end
                bool hit = d2 < R2C;
                unsigned long long mask = __ballot(hit);
                if (hit) {
                    int pos = cnt[p] + __builtin_amdgcn_mbcnt_hi(
                                 (unsigned)(mask >> 32),
                                 __builtin_amdgcn_mbcnt_lo((unsigned)mask, 0));
                    if (pos < KK) sidx[4 * w + p][pos] = m;
                }
                cnt[p] += __popcll(mask);
            }
        }
        __syncthreads();

        float lsum = 0.0f;
#pragma unroll
        for (int p = 0; p < 4; ++p) {
            int row = 4 * w + p;
            if (lane < KK) {
                int fillv = (cnt[p] > 0) ? sidx[row][0] : 0;
                if (lane >= cnt[p]) sidx[row][lane] = fillv;
            }
            float mv = mn[p];
            for (int off = 32; off > 0; off >>= 1)
                mv = fminf(mv, __shfl_xor(mv, off));
            lsum += sqrtf(1e-6f + fmaxf(mv, 0.0f));
        }
        if (lane == 0)
            atomicAdd(lossbuf + ((blk * 4 + w) & 1023) * 8,
                      lsum * (1.0f / (BB * NN)));
        __syncthreads();
        if (t == 0) {
            __threadfence();
            rflag = (atomicAdd(counter, 1) == 1023) ? 1 : 0;
        }
        __syncthreads();
        if (rflag) {
            float s = 0.0f;
#pragma unroll
            for (int q = 0; q < 4; ++q)
                s += __hip_atomic_load(lossbuf + (t + 256 * q) * 8,
                                       __ATOMIC_RELAXED, __HIP_MEMORY_SCOPE_AGENT);
            for (int off = 32; off > 0; off >>= 1) s += __shfl_xor(s, off);
            if ((t & 63) == 0) ws4v[t >> 6] = s;
            __syncthreads();
            if (t == 0)
                out[(size_t)BB * 64 * NN] = ws4v[0] + ws4v[1] + ws4v[2] + ws4v[3];
        }

        // ================ phase B: MLP for the 16 points ================
        int quad = lane >> 4, lc = lane & 15;
        size_t bM = (size_t)b * MM;
        int n0 = pt0;

        v8h a1[2][3], a2[4], a3[2];
#pragma unroll
        for (int rt = 0; rt < 2; ++rt)
#pragma unroll
            for (int ks = 0; ks < 3; ++ks)
                a1[rt][ks] = *(const v8h*)(w1h + (32 * w + 16 * rt + lc) * 96 + 32 * ks + 8 * quad);
#pragma unroll
        for (int ks = 0; ks < 4; ++ks)
            a2[ks] = *(const v8h*)(w2h + (16 * w + lc) * 128 + 32 * ks + 8 * quad);
#pragma unroll
        for (int ks = 0; ks < 2; ++ks)
            a3[ks] = *(const v8h*)(w3h + (16 * w + lc) * 64 + 32 * ks + 8 * quad);

        v4f bias1a = *(const v4f*)(b1 + 32 * w + 4 * quad);
        v4f bias1b = *(const v4f*)(b1 + 32 * w + 16 + 4 * quad);
        v4f bias2  = *(const v4f*)(b2 + 16 * w + 4 * quad);
        v4f bias3  = *(const v4f*)(b3 + 16 * w + 4 * quad);

#pragma unroll 1
        for (int ps = 0; ps < 8; ++ps) {
            // ---- stage X: 4 threads per column, ids from LDS sidx ----
            {
                int col = t >> 2, h = t & 3;
                int pl = col >> 5, kk = col & 31;
                int lrow = 2 * ps + pl;
                int id = sidx[lrow][kk];
                const v8h* src = (const v8h*)(featH + (bM + id) * CC) + h * 2;
                v8h f0 = src[0], f1 = src[1];
                v8h* dst = (v8h*)(X + col * XS) + h * 2;
                dst[0] = f0; dst[1] = f1;
                v8h mv = {(_Float16)0.f, (_Float16)0.f, (_Float16)0.f, (_Float16)0.f,
                          (_Float16)0.f, (_Float16)0.f, (_Float16)0.f, (_Float16)0.f};
                if (h == 0) {
                    float4 p4 = pointsT[n0 + lrow];
                    float4 nb = knnT[bM + id];
                    float dx = nb.x - p4.x, dy = nb.y - p4.y, dz = nb.z - p4.z;
                    float dd = __fadd_rn(__fadd_rn(__fmul_rn(dx, dx), __fmul_rn(dy, dy)),
                                         __fmul_rn(dz, dz));
                    mv[0] = (_Float16)dx; mv[1] = (_Float16)dy;
                    mv[2] = (_Float16)dz; mv[3] = (_Float16)dd;
                }
                *((v8h*)(X + col * XS + 64) + h) = mv;   // meta + zero pad
            }
            __syncthreads();

            // ---- layer 1: H1(128 x 64) = W1 x X ----
#pragma unroll 1
            for (int ct = 0; ct < 4; ++ct) {
                int colb = 16 * ct + lc;
                v4f acc0 = bias1a, acc1 = bias1b;
#pragma unroll
                for (int ks = 0; ks < 3; ++ks) {
                    v8h bx = *(const v8h*)(X + colb * XS + 32 * ks + 8 * quad);
                    acc0 = __builtin_amdgcn_mfma_f32_16x16x32_f16(a1[0][ks], bx, acc0, 0, 0, 0);
                    acc1 = __builtin_amdgcn_mfma_f32_16x16x32_f16(a1[1][ks], bx, acc1, 0, 0, 0);
                }
                v4h h0, h1v;
#pragma unroll
                for (int r = 0; r < 4; ++r) {
                    h0[r]  = (_Float16)fmaxf(acc0[r], 0.0f);
                    h1v[r] = (_Float16)fmaxf(acc1[r], 0.0f);
                }
                *(v4h*)(H1 + colb * H1S + 32 * w + 4 * quad)      = h0;
                *(v4h*)(H1 + colb * H1S + 32 * w + 16 + 4 * quad) = h1v;
            }
            __syncthreads();   // X consumed; H2 may overwrite

            // ---- layer 2: H2(64 x 64) = W2 x H1 ----
#pragma unroll 1
            for (int ct = 0; ct < 4; ++ct) {
                int colb = 16 * ct + lc;
                v4f acc = bias2;
#pragma unroll
                for (int ks = 0; ks < 4; ++ks) {
                    v8h bx = *(const v8h*)(H1 + colb * H1S + 32 * ks + 8 * quad);
                    acc = __builtin_amdgcn_mfma_f32_16x16x32_f16(a2[ks], bx, acc, 0, 0, 0);
                }
                v4h h;
#pragma unroll
                for (int r = 0; r < 4; ++r) h[r] = (_Float16)fmaxf(acc[r], 0.0f);
                *(v4h*)(H2 + colb * H2S + 16 * w + 4 * quad) = h;
            }
            __syncthreads();

            // ---- layer 3 + ReLU + sum over k + store agg ----
#pragma unroll 1
            for (int p = 0; p < 2; ++p) {
                int cA = (2 * p) * 16 + lc, cB = (2 * p + 1) * 16 + lc;
                v4f accA = bias3, accB = bias3;
#pragma unroll
                for (int ks = 0; ks < 2; ++ks) {
                    v8h bA = *(const v8h*)(H2 + cA * H2S + 32 * ks + 8 * quad);
                    v8h bB = *(const v8h*)(H2 + cB * H2S + 32 * ks + 8 * quad);
                    accA = __builtin_amdgcn_mfma_f32_16x16x32_f16(a3[ks], bA, accA, 0, 0, 0);
                    accB = __builtin_amdgcn_mfma_f32_16x16x32_f16(a3[ks], bB, accB, 0, 0, 0);
                }
                v4f s;
#pragma unroll
                for (int r = 0; r < 4; ++r)
                    s[r] = fmaxf(accA[r], 0.0f) + fmaxf(accB[r], 0.0f);
#pragma unroll
                for (int off = 1; off < 16; off <<= 1) {
#pragma unroll
                    for (int r = 0; r < 4; ++r) s[r] += __shfl_xor(s[r], off);
                }
                if (lc == 0) {
                    int nloc = (n0 & (NN - 1)) + 2 * ps + p;
                    int rowb = 16 * w + 4 * quad;
#pragma unroll
                    for (int r = 0; r < 4; ++r)
                        out[((size_t)(b * 64 + rowb + r)) * NN + nloc] = s[r];
                }
            }
            __syncthreads();   // protect X/H1 before next pass staging
        }
    } else {
        // ================ colmin: 16 m per block ================
        int blk2 = blk - 512;
        int m0 = blk2 * 16;                  // global knn id (b*MM+m)
        int b = m0 >> 12;
        float4 Kp[4];
#pragma unroll
        for (int p = 0; p < 4; ++p) Kp[p] = knnT[m0 + 4 * w + p];
        float mn[4] = {1e30f, 1e30f, 1e30f, 1e30f};
        const float4* pb = pointsT + (size_t)b * NN;

#pragma unroll 2
        for (int c = 0; c < NN / 64; ++c) {
            float4 p4 = pb[c * 64 + lane];
#pragma unroll
            for (int p = 0; p < 4; ++p) {
                float cross = __builtin_fmaf(p4.z, Kp[p].z,
                              __builtin_fmaf(p4.y, Kp[p].y,
                                             __fmul_rn(p4.x, Kp[p].x)));
                float d2 = __fsub_rn(__fadd_rn(p4.w, Kp[p].w),
                                     __fmul_rn(2.0f, cross));
                mn[p] = fminf(mn[p], d2);
            }
        }

        float lsum = 0.0f;
#pragma unroll
        for (int p = 0; p < 4; ++p) {
            float mv = mn[p];
            for (int off = 32; off > 0; off >>= 1)
                mv = fminf(mv, __shfl_xor(mv, off));
            lsum += sqrtf(1e-6f + fmaxf(mv, 0.0f));
        }
        if (lane == 0)
            atomicAdd(lossbuf + ((blk2 * 4 + w) & 1023) * 8,
                      lsum * (1.0f / (BB * MM)));
        __syncthreads();
        if (t == 0) {
            __threadfence();
            rflag = (atomicAdd(counter, 1) == 1023) ? 1 : 0;
        }
        __syncthreads();
        if (rflag) {
            float s = 0.0f;
#pragma unroll
            for (int q = 0; q < 4; ++q)
                s += __hip_atomic_load(lossbuf + (t + 256 * q) * 8,
                                       __ATOMIC_RELAXED, __HIP_MEMORY_SCOPE_AGENT);
            for (int off = 32; off > 0; off >>= 1) s += __shfl_xor(s, off);
            if ((t & 63) == 0) ws4v[t >> 6] = s;
            __syncthreads();
            if (t == 0)
                out[(size_t)BB * 64 * NN] = ws4v[0] + ws4v[1] + ws4v[2] + ws4v[3];
        }
    }
}

// ---------------------------------------------------------------------------
extern "C" void kernel_launch(void* const* d_in, const int* in_sizes, int n_in,
                              void* d_out, int out_size, void* d_ws, size_t ws_size,
                              hipStream_t stream) {
    const float* points = (const float*)d_in[0];
    const float* knn    = (const float*)d_in[1];
    const float* feat   = (const float*)d_in[2];
    const float* w1 = (const float*)d_in[3];
    const float* b1 = (const float*)d_in[4];
    const float* w2 = (const float*)d_in[5];
    const float* b2 = (const float*)d_in[6];
    const float* w3 = (const float*)d_in[7];
    const float* b3 = (const float*)d_in[8];
    float* out = (float*)d_out;

    char* ws = (char*)d_ws;
    float4*    pointsT = (float4*)ws;                    // 131072 B
    float4*    knnT    = (float4*)(ws + 131072);         // 131072 B
    _Float16*  featH   = (_Float16*)(ws + 262144);       // 1048576 B
    _Float16*  w1h     = (_Float16*)(ws + 1310720);      // 24576 B
    _Float16*  w2h     = (_Float16*)(ws + 1335296);      // 16384 B
    _Float16*  w3h     = (_Float16*)(ws + 1351680);      // 8192 B
    float*     lossbuf = (float*)(ws + 1359872);         // 32768 B
    int*       counter = (int*)(ws + 1392640);           // 4 B

    setup_kernel<<<248, 256, 0, stream>>>(points, knn, feat, w1, w2, w3,
                                          pointsT, knnT, featH, w1h, w2h, w3h,
                                          lossbuf, counter);
    fused_kernel<<<1024, 256, 0, stream>>>(pointsT, knnT, featH,
                                           w1h, b1, w2h, b2, w3h, b3,
                                           lossbuf, counter, out);
}

// Round 8
// 118.390 us; speedup vs baseline: 1.2055x; 1.2055x over previous
//
#include <hip/hip_runtime.h>
#include <cstdint>

#define BB 2
#define NN 4096
#define MM 4096
#define KK 32
#define CC 64
#define R2C 0.0064f   // RADIUS^2

typedef _Float16 v8h __attribute__((ext_vector_type(8)));
typedef _Float16 v4h __attribute__((ext_vector_type(4)));
typedef float    v4f __attribute__((ext_vector_type(4)));

#define TC  64     // MLP columns per block
#define XS  104    // X  stride (f16): 96 + 8 pad
#define H1S 136    // H1 stride: 128 + 8
#define H2S 72     // H2 stride: 64 + 8

// ---------------------------------------------------------------------------
// Dispatch 1: scan + setup in one kernel (no inter-block dependencies).
//   blocks [   0,  512): SELECT 16 points (4/wave). knnT chunks staged to LDS
//                        from the RAW (B,3,M) layout with |k|^2 computed in
//                        the staging pass (identical fp32 op order to the
//                        old setup -> identical d2 bits -> identical
//                        selection). Ballot-compaction of the first KK
//                        ascending in-radius m == reference
//                        top_k-of-masked-index. Row-min -> unique loss slot.
//   blocks [ 512, 1024): COLMIN 16 m (4/wave), points staged likewise.
//   blocks [1024, 1152): transpose feat (B,C,M) -> featH (B,M,C) f16.
//   blocks [1152, 1200): pack weights to f16 A-operand layouts.
// Loss: per-wave plain store to a unique slot (no atomics, no zeroing).
// ---------------------------------------------------------------------------
__launch_bounds__(256)
__global__ void scan_setup_kernel(const float* __restrict__ points,
                                  const float* __restrict__ knn,
                                  const float* __restrict__ feat,
                                  const float* __restrict__ w1,
                                  const float* __restrict__ w2,
                                  const float* __restrict__ w3,
                                  _Float16* __restrict__ featH,
                                  _Float16* __restrict__ w1h,
                                  _Float16* __restrict__ w2h,
                                  _Float16* __restrict__ w3h,
                                  int* __restrict__ idx_ws,
                                  float* __restrict__ lossbuf) {
    __shared__ __align__(16) char SM[16640];   // union: float4[1024] | float[64][65]
    __shared__ int sidx[16][KK];
    float4* tile = (float4*)SM;
    int t = threadIdx.x;
    int w = t >> 6, lane = t & 63;
    int blk = blockIdx.x;

    if (blk < 512) {
        // ---------------- select ----------------
        int pt0 = blk * 16;                  // global point id (b*NN+n)
        int b = blk >> 8;
        const float* pp = points + (size_t)b * 3 * NN;
        const float* kp = knn + (size_t)b * 3 * MM;
        float4 P[4];
#pragma unroll
        for (int p = 0; p < 4; ++p) {
            int nl = (pt0 & (NN - 1)) + 4 * w + p;
            float x = pp[nl], y = pp[NN + nl], z = pp[2 * NN + nl];
            float e = __fadd_rn(__fadd_rn(__fmul_rn(x, x), __fmul_rn(y, y)),
                                __fmul_rn(z, z));
            P[p] = make_float4(x, y, z, e);
        }
        int cnt[4] = {0, 0, 0, 0};
        float mn[4] = {1e30f, 1e30f, 1e30f, 1e30f};

        for (int ch = 0; ch < 4; ++ch) {
            const float* kx = kp + ch * 1024;
#pragma unroll
            for (int j = 0; j < 4; ++j) {
                int i = t + 256 * j;
                float x = kx[i], y = kx[MM + i], z = kx[2 * MM + i];
                float e = __fadd_rn(__fadd_rn(__fmul_rn(x, x), __fmul_rn(y, y)),
                                    __fmul_rn(z, z));
                tile[i] = make_float4(x, y, z, e);
            }
            __syncthreads();
#pragma unroll 2
            for (int i = 0; i < 16; ++i) {
                float4 k4 = tile[i * 64 + lane];
                int m = ch * 1024 + i * 64 + lane;
#pragma unroll
                for (int p = 0; p < 4; ++p) {
                    float cross = __builtin_fmaf(P[p].z, k4.z,
                                  __builtin_fmaf(P[p].y, k4.y,
                                                 __fmul_rn(P[p].x, k4.x)));
                    float d2 = __fsub_rn(__fadd_rn(P[p].w, k4.w),
                                         __fmul_rn(2.0f, cross));
                    mn[p] = fminf(mn[p], d2);        // clamp once at end
                    bool hit = d2 < R2C;
                    unsigned long long mask = __ballot(hit);
                    if (hit) {
                        int pos = cnt[p] + __builtin_amdgcn_mbcnt_hi(
                                     (unsigned)(mask >> 32),
                                     __builtin_amdgcn_mbcnt_lo((unsigned)mask, 0));
                        if (pos < KK) sidx[4 * w + p][pos] = m;
                    }
                    cnt[p] += __popcll(mask);
                }
            }
            __syncthreads();
        }

        float lsum = 0.0f;
#pragma unroll
        for (int p = 0; p < 4; ++p) {
            int row = 4 * w + p;
            if (lane < KK) {
                int fillv = (cnt[p] > 0) ? sidx[row][0] : 0;
                int v = (lane < cnt[p]) ? sidx[row][lane] : fillv;
                idx_ws[((size_t)(pt0 + row)) * KK + lane] = v;
            }
            float mv = mn[p];
            for (int off = 32; off > 0; off >>= 1)
                mv = fminf(mv, __shfl_xor(mv, off));
            lsum += sqrtf(1e-6f + fmaxf(mv, 0.0f));
        }
        if (lane == 0)
            lossbuf[blk * 4 + w] = lsum * (1.0f / (BB * NN));
    } else if (blk < 1024) {
        // ---------------- colmin ----------------
        int blk2 = blk - 512;
        int m0 = blk2 * 16;                  // global knn id (b*MM+m)
        int b = blk2 >> 8;
        const float* pp = points + (size_t)b * 3 * NN;
        const float* kp = knn + (size_t)b * 3 * MM;
        float4 Kp[4];
#pragma unroll
        for (int p = 0; p < 4; ++p) {
            int ml = (m0 & (MM - 1)) + 4 * w + p;
            float x = kp[ml], y = kp[MM + ml], z = kp[2 * MM + ml];
            float e = __fadd_rn(__fadd_rn(__fmul_rn(x, x), __fmul_rn(y, y)),
                                __fmul_rn(z, z));
            Kp[p] = make_float4(x, y, z, e);
        }
        float mn[4] = {1e30f, 1e30f, 1e30f, 1e30f};

        for (int ch = 0; ch < 4; ++ch) {
            const float* px = pp + ch * 1024;
#pragma unroll
            for (int j = 0; j < 4; ++j) {
                int i = t + 256 * j;
                float x = px[i], y = px[NN + i], z = px[2 * NN + i];
                float e = __fadd_rn(__fadd_rn(__fmul_rn(x, x), __fmul_rn(y, y)),
                                    __fmul_rn(z, z));
                tile[i] = make_float4(x, y, z, e);
            }
            __syncthreads();
#pragma unroll 2
            for (int i = 0; i < 16; ++i) {
                float4 p4 = tile[i * 64 + lane];
#pragma unroll
                for (int p = 0; p < 4; ++p) {
                    float cross = __builtin_fmaf(p4.z, Kp[p].z,
                                  __builtin_fmaf(p4.y, Kp[p].y,
                                                 __fmul_rn(p4.x, Kp[p].x)));
                    float d2 = __fsub_rn(__fadd_rn(p4.w, Kp[p].w),
                                         __fmul_rn(2.0f, cross));
                    mn[p] = fminf(mn[p], d2);
                }
            }
            __syncthreads();
        }

        float lsum = 0.0f;
#pragma unroll
        for (int p = 0; p < 4; ++p) {
            float mv = mn[p];
            for (int off = 32; off > 0; off >>= 1)
                mv = fminf(mv, __shfl_xor(mv, off));
            lsum += sqrtf(1e-6f + fmaxf(mv, 0.0f));
        }
        if (lane == 0)
            lossbuf[2048 + blk2 * 4 + w] = lsum * (1.0f / (BB * MM));
    } else if (blk < 1152) {
        // ---------------- feat transpose ----------------
        float (*tl)[65] = (float (*)[65])SM;
        int tb = blk - 1024;                    // 128 tiles
        int b = tb / (MM / 64);
        int m0 = (tb % (MM / 64)) * 64;
        int mi = t & 63, cq = t >> 6;
        const float* src = feat + (size_t)b * CC * MM;
#pragma unroll
        for (int r = 0; r < 16; ++r) {
            int c = cq * 16 + r;
            tl[mi][c] = src[(size_t)c * MM + m0 + mi];
        }
        __syncthreads();
        int ci = t & 63, mq = t >> 6;
        _Float16* dst = featH + ((size_t)b * MM + m0) * CC;
#pragma unroll
        for (int r = 0; r < 16; ++r) {
            int mm = mq * 16 + r;
            dst[(size_t)mm * CC + ci] = (_Float16)tl[mm][ci];
        }
    } else {
        // ---------------- weight pack ----------------
        int tt = (blk - 1152) * 256 + t;        // < 12288
        if (tt < 128 * 96) {
            int r = tt / 96, k = tt - r * 96;
            w1h[tt] = (_Float16)((k < 68) ? w1[r * 68 + k] : 0.0f);
        }
        if (tt < 64 * 128) w2h[tt] = (_Float16)w2[tt];
        if (tt < 64 * 64)  w3h[tt] = (_Float16)w3[tt];
    }
}

// ---------------------------------------------------------------------------
// Dispatch 2: MFMA MLP. WG = 256 thr = 4 waves, 64 columns (2 points x 32 k).
// LDS: H2 aliases X (X dead after layer-1 barrier) -> 30720 B, 4 blocks/CU.
// Block 0 additionally sums the 4096 loss partial slots (previous dispatch,
// stream-ordered -> visible) and writes out[loss].
// A-frag: A[m=lane&15][k=quad*8+j]; C-frag: col=lane&15, row=quad*4+reg.
// ---------------------------------------------------------------------------
__launch_bounds__(256, 4)
__global__ void mlp_kernel(const float* __restrict__ points,
                           const float* __restrict__ knn,
                           const _Float16* __restrict__ featH,
                           const int* __restrict__ idx_ws,
                           const _Float16* __restrict__ w1h, const float* __restrict__ b1,
                           const _Float16* __restrict__ w2h, const float* __restrict__ b2,
                           const _Float16* __restrict__ w3h, const float* __restrict__ b3,
                           const float* __restrict__ lossbuf,
                           float* __restrict__ out) {
    __shared__ __align__(16) _Float16 SM[TC * XS + TC * H1S];  // 30720 B
    _Float16* X  = SM;
    _Float16* H2 = SM;             // aliases X (dead after layer-1 barrier)
    _Float16* H1 = SM + TC * XS;
    __shared__ float ws4[4];

    int t = threadIdx.x;

    // ---- fused loss reduction (block 0 only) ----
    if (blockIdx.x == 0) {
        float s = 0.0f;
#pragma unroll
        for (int q = 0; q < 16; ++q) s += lossbuf[t + 256 * q];
        for (int off = 32; off > 0; off >>= 1) s += __shfl_xor(s, off);
        if ((t & 63) == 0) ws4[t >> 6] = s;
        __syncthreads();
        if (t == 0)
            out[(size_t)BB * 64 * NN] = ws4[0] + ws4[1] + ws4[2] + ws4[3];
    }

    int point0 = blockIdx.x * 2;
    int b = point0 >> 12;
    int n0 = point0 & (NN - 1);
    const float* pp = points + (size_t)b * 3 * NN;
    const float* kp = knn + (size_t)b * 3 * MM;

    // ---- stage X tile: 4 threads per column ----
    {
        int col = t >> 2, h = t & 3;
        int pl = col >> 5, kk = col & 31;
        int n = n0 + pl;
        int id = idx_ws[(((size_t)b * NN + n) << 5) + kk];
        const v8h* src = (const v8h*)(featH + ((size_t)(b * MM + id)) * CC) + h * 2;
        v8h f0 = src[0], f1 = src[1];
        v8h* dst = (v8h*)(X + col * XS) + h * 2;
        dst[0] = f0; dst[1] = f1;
        v8h mv = {(_Float16)0.f, (_Float16)0.f, (_Float16)0.f, (_Float16)0.f,
                  (_Float16)0.f, (_Float16)0.f, (_Float16)0.f, (_Float16)0.f};
        if (h == 0) {
            float px = pp[n], py = pp[NN + n], pz = pp[2 * NN + n];
            float kx = kp[id], ky = kp[MM + id], kz = kp[2 * MM + id];
            float dx = kx - px, dy = ky - py, dz = kz - pz;
            float dd = __fadd_rn(__fadd_rn(__fmul_rn(dx, dx), __fmul_rn(dy, dy)),
                                 __fmul_rn(dz, dz));
            mv[0] = (_Float16)dx; mv[1] = (_Float16)dy;
            mv[2] = (_Float16)dz; mv[3] = (_Float16)dd;
        }
        *((v8h*)(X + col * XS + 64) + h) = mv;   // meta + zero-pad [64,96)
    }

    int w = t >> 6, l = t & 63;
    int quad = l >> 4, lc = l & 15;

    // ---- preload A-fragments (weights) ----
    v8h a1[2][3], a2[4], a3[2];
#pragma unroll
    for (int rt = 0; rt < 2; ++rt)
#pragma unroll
        for (int ks = 0; ks < 3; ++ks)
            a1[rt][ks] = *(const v8h*)(w1h + (32 * w + 16 * rt + lc) * 96 + 32 * ks + 8 * quad);
#pragma unroll
    for (int ks = 0; ks < 4; ++ks)
        a2[ks] = *(const v8h*)(w2h + (16 * w + lc) * 128 + 32 * ks + 8 * quad);
#pragma unroll
    for (int ks = 0; ks < 2; ++ks)
        a3[ks] = *(const v8h*)(w3h + (16 * w + lc) * 64 + 32 * ks + 8 * quad);

    v4f bias1a = *(const v4f*)(b1 + 32 * w + 4 * quad);
    v4f bias1b = *(const v4f*)(b1 + 32 * w + 16 + 4 * quad);
    v4f bias2  = *(const v4f*)(b2 + 16 * w + 4 * quad);
    v4f bias3  = *(const v4f*)(b3 + 16 * w + 4 * quad);

    __syncthreads();

    // ---- layer 1: H1(128 x 64cols) = W1 x X ----
#pragma unroll 1
    for (int ct = 0; ct < 4; ++ct) {
        int colb = 16 * ct + lc;
        v4f acc0 = bias1a, acc1 = bias1b;
#pragma unroll
        for (int ks = 0; ks < 3; ++ks) {
            v8h bx = *(const v8h*)(X + colb * XS + 32 * ks + 8 * quad);
            acc0 = __builtin_amdgcn_mfma_f32_16x16x32_f16(a1[0][ks], bx, acc0, 0, 0, 0);
            acc1 = __builtin_amdgcn_mfma_f32_16x16x32_f16(a1[1][ks], bx, acc1, 0, 0, 0);
        }
        v4h h0, h1v;
#pragma unroll
        for (int r = 0; r < 4; ++r) {
            h0[r]  = (_Float16)fmaxf(acc0[r], 0.0f);
            h1v[r] = (_Float16)fmaxf(acc1[r], 0.0f);
        }
        *(v4h*)(H1 + colb * H1S + 32 * w + 4 * quad)      = h0;
        *(v4h*)(H1 + colb * H1S + 32 * w + 16 + 4 * quad) = h1v;
    }
    __syncthreads();   // X fully consumed; H2 may now overwrite it

    // ---- layer 2: H2(64 x 64cols) = W2 x H1 ----
#pragma unroll 1
    for (int ct = 0; ct < 4; ++ct) {
        int colb = 16 * ct + lc;
        v4f acc = bias2;
#pragma unroll
        for (int ks = 0; ks < 4; ++ks) {
            v8h bx = *(const v8h*)(H1 + colb * H1S + 32 * ks + 8 * quad);
            acc = __builtin_amdgcn_mfma_f32_16x16x32_f16(a2[ks], bx, acc, 0, 0, 0);
        }
        v4h h;
#pragma unroll
        for (int r = 0; r < 4; ++r) h[r] = (_Float16)fmaxf(acc[r], 0.0f);
        *(v4h*)(H2 + colb * H2S + 16 * w + 4 * quad) = h;
    }
    __syncthreads();

    // ---- layer 3 + ReLU + sum over k + store agg ----
#pragma unroll 1
    for (int p = 0; p < 2; ++p) {
        int cA = (2 * p) * 16 + lc, cB = (2 * p + 1) * 16 + lc;
        v4f accA = bias3, accB = bias3;
#pragma unroll
        for (int ks = 0; ks < 2; ++ks) {
            v8h bA = *(const v8h*)(H2 + cA * H2S + 32 * ks + 8 * quad);
            v8h bB = *(const v8h*)(H2 + cB * H2S + 32 * ks + 8 * quad);
            accA = __builtin_amdgcn_mfma_f32_16x16x32_f16(a3[ks], bA, accA, 0, 0, 0);
            accB = __builtin_amdgcn_mfma_f32_16x16x32_f16(a3[ks], bB, accB, 0, 0, 0);
        }
        v4f s;
#pragma unroll
        for (int r = 0; r < 4; ++r)
            s[r] = fmaxf(accA[r], 0.0f) + fmaxf(accB[r], 0.0f);
#pragma unroll
        for (int off = 1; off < 16; off <<= 1) {
#pragma unroll
            for (int r = 0; r < 4; ++r) s[r] += __shfl_xor(s[r], off);
        }
        if (lc == 0) {
            int n = n0 + p;
            int rowb = 16 * w + 4 * quad;
#pragma unroll
            for (int r = 0; r < 4; ++r)
                out[((size_t)(b * 64 + rowb + r)) * NN + n] = s[r];
        }
    }
}

// ---------------------------------------------------------------------------
extern "C" void kernel_launch(void* const* d_in, const int* in_sizes, int n_in,
                              void* d_out, int out_size, void* d_ws, size_t ws_size,
                              hipStream_t stream) {
    const float* points = (const float*)d_in[0];
    const float* knn    = (const float*)d_in[1];
    const float* feat   = (const float*)d_in[2];
    const float* w1 = (const float*)d_in[3];
    const float* b1 = (const float*)d_in[4];
    const float* w2 = (const float*)d_in[5];
    const float* b2 = (const float*)d_in[6];
    const float* w3 = (const float*)d_in[7];
    const float* b3 = (const float*)d_in[8];
    float* out = (float*)d_out;

    char* ws = (char*)d_ws;
    _Float16*  featH   = (_Float16*)ws;                  // 1048576 B
    int*       idx_ws  = (int*)(ws + 1048576);           // 1048576 B
    _Float16*  w1h     = (_Float16*)(ws + 2097152);      // 24576 B
    _Float16*  w2h     = (_Float16*)(ws + 2121728);      // 16384 B
    _Float16*  w3h     = (_Float16*)(ws + 2138112);      // 8192 B
    float*     lossbuf = (float*)(ws + 2146304);         // 16384 B (4096 slots)

    scan_setup_kernel<<<1200, 256, 0, stream>>>(points, knn, feat, w1, w2, w3,
                                                featH, w1h, w2h, w3h,
                                                idx_ws, lossbuf);
    mlp_kernel<<<(BB * NN) / 2, 256, 0, stream>>>(points, knn, featH, idx_ws,
                                                  w1h, b1, w2h, b2, w3h, b3,
                                                  lossbuf, out);
}